// Round 1
// baseline (640.175 us; speedup 1.0000x reference)
//
#include <hip/hip_runtime.h>
#include <math.h>

constexpr int Lq = 8, Cq = 16, Hq = 240, Wq = 480, Rq = 8, MIDq = 8, SEM = 4;
constexpr int HWq = Hq * Wq;

__device__ __forceinline__ float sigmoidf_(float v) { return 1.0f / (1.0f + expf(-v)); }

// conv1: x (L,16,H,W) -> silu -> f1 (L,8,H,W), 3x3 SAME zero-pad
__global__ void k_conv1(const float* __restrict__ x, const float* __restrict__ w1,
                        const float* __restrict__ b1, float* __restrict__ f1) {
    __shared__ float wl[MIDq * Cq * 9];
    __shared__ float bl[MIDq];
    int tid = threadIdx.x;
    for (int i = tid; i < MIDq * Cq * 9; i += blockDim.x) wl[i] = w1[i];
    if (tid < MIDq) bl[tid] = b1[tid];
    __syncthreads();
    int idx = blockIdx.x * blockDim.x + tid;
    if (idx >= Lq * HWq) return;
    int l = idx / HWq, rem = idx % HWq, y = rem / Wq, xx = rem % Wq;
    float acc[MIDq];
#pragma unroll
    for (int m = 0; m < MIDq; m++) acc[m] = bl[m];
    for (int ic = 0; ic < Cq; ic++) {
        const float* xin = x + (size_t)(l * Cq + ic) * HWq;
#pragma unroll
        for (int dy = -1; dy <= 1; dy++) {
            int yy = y + dy;
            if (yy < 0 || yy >= Hq) continue;
#pragma unroll
            for (int dx = -1; dx <= 1; dx++) {
                int xc = xx + dx;
                if (xc < 0 || xc >= Wq) continue;
                float v = xin[yy * Wq + xc];
                const float* wp = &wl[ic * 9 + (dy + 1) * 3 + (dx + 1)];
#pragma unroll
                for (int m = 0; m < MIDq; m++) acc[m] = fmaf(wp[m * Cq * 9], v, acc[m]);
            }
        }
    }
#pragma unroll
    for (int m = 0; m < MIDq; m++) {
        float v = acc[m];
        f1[(size_t)(l * MIDq + m) * HWq + rem] = v * sigmoidf_(v);
    }
}

// conv2: f1 (L,8,H,W) -> f (L,2,H,W), 3x3 SAME zero-pad (phi=ch0, psi=ch1)
__global__ void k_conv2(const float* __restrict__ f1, const float* __restrict__ w2,
                        const float* __restrict__ b2, float* __restrict__ f) {
    __shared__ float wl[2 * MIDq * 9];
    __shared__ float bl[2];
    int tid = threadIdx.x;
    for (int i = tid; i < 2 * MIDq * 9; i += blockDim.x) wl[i] = w2[i];
    if (tid < 2) bl[tid] = b2[tid];
    __syncthreads();
    int idx = blockIdx.x * blockDim.x + tid;
    if (idx >= Lq * HWq) return;
    int l = idx / HWq, rem = idx % HWq, y = rem / Wq, xx = rem % Wq;
    float acc0 = bl[0], acc1 = bl[1];
    for (int ic = 0; ic < MIDq; ic++) {
        const float* fin = f1 + (size_t)(l * MIDq + ic) * HWq;
#pragma unroll
        for (int dy = -1; dy <= 1; dy++) {
            int yy = y + dy;
            if (yy < 0 || yy >= Hq) continue;
#pragma unroll
            for (int dx = -1; dx <= 1; dx++) {
                int xc = xx + dx;
                if (xc < 0 || xc >= Wq) continue;
                float v = fin[yy * Wq + xc];
                int wi = ic * 9 + (dy + 1) * 3 + (dx + 1);
                acc0 = fmaf(wl[wi], v, acc0);
                acc1 = fmaf(wl[MIDq * 9 + wi], v, acc1);
            }
        }
    }
    f[(size_t)(l * 2 + 0) * HWq + rem] = acc0;
    f[(size_t)(l * 2 + 1) * HWq + rem] = acc1;
}

// sobel (wrap-x, edge-y) + metric + tanh -> flow (L,2,H,W)
__global__ void k_flow(const float* __restrict__ f, float* __restrict__ flow) {
    int idx = blockIdx.x * blockDim.x + threadIdx.x;
    if (idx >= Lq * HWq) return;
    int l = idx / HWq, rem = idx % HWq, y = rem / Wq, x = rem % Wq;
    const float* phi = f + (size_t)(l * 2 + 0) * HWq;
    const float* psi = f + (size_t)(l * 2 + 1) * HWq;
    float ph[3][3], ps[3][3];
#pragma unroll
    for (int i = 0; i < 3; i++) {
        int yy = y + i - 1;
        yy = yy < 0 ? 0 : (yy >= Hq ? Hq - 1 : yy);
#pragma unroll
        for (int j = 0; j < 3; j++) {
            int xx = x + j - 1;
            xx = (xx + Wq) % Wq;
            ph[i][j] = phi[yy * Wq + xx];
            ps[i][j] = psi[yy * Wq + xx];
        }
    }
    float gxp = (ph[0][2] - ph[0][0]) + 2.f * (ph[1][2] - ph[1][0]) + (ph[2][2] - ph[2][0]);
    float gyp = (ph[2][0] + 2.f * ph[2][1] + ph[2][2]) - (ph[0][0] + 2.f * ph[0][1] + ph[0][2]);
    float gxs = (ps[0][2] - ps[0][0]) + 2.f * (ps[1][2] - ps[1][0]) + (ps[2][2] - ps[2][0]);
    float gys = (ps[2][0] + 2.f * ps[2][1] + ps[2][2]) - (ps[0][0] + 2.f * ps[0][1] + ps[0][2]);
    // lat endpoints must cast to the exact f32 linspace endpoints; cos in double
    float latf = (float)(-M_PI * 0.5 + (double)y * (M_PI / (double)(Hq - 1)));
    float metric = (float)(1.0 / (cos((double)latf) + 1e-6));
    float u = gxp * metric - gys;
    float v = gyp + gxs * metric;
    flow[(size_t)(l * 2 + 0) * HWq + rem] = tanhf(u);
    flow[(size_t)(l * 2 + 1) * HWq + rem] = tanhf(v);
}

// warp (bilinear, border clamp) + add x_t + mean over R + row partial sums
// block = one (c,y) row; grid = C*H
__global__ void k_warp(const float* __restrict__ hin, float* __restrict__ hout,
                       const float* __restrict__ flow_l, const float* __restrict__ xl,
                       const float* __restrict__ listT, int l,
                       float* __restrict__ xf, float* __restrict__ rowsum) {
    int c = blockIdx.x / Hq, y = blockIdx.x % Hq;
    int tid = threadIdx.x;
    float dt = listT[l];
    float gyn = y * (2.0f / (Hq - 1)) - 1.0f;
    const float4* h4 = (const float4*)hin;
    float4* o4 = (float4*)hout;
    float partial = 0.f;
    for (int x = tid; x < Wq; x += blockDim.x) {
        float u = flow_l[y * Wq + x];
        float v = flow_l[HWq + y * Wq + x];
        float gxn = x * (2.0f / (Wq - 1)) - 1.0f;
        float gx = gxn - u * dt;
        float gy = gyn - v * dt;
        float xp = (gx + 1.0f) * (Wq * 0.5f) - 0.5f;
        float yp = (gy + 1.0f) * (Hq * 0.5f) - 0.5f;
        xp = fminf(fmaxf(xp, 0.0f), (float)(Wq - 1));
        yp = fminf(fmaxf(yp, 0.0f), (float)(Hq - 1));
        float x0f = floorf(xp), y0f = floorf(yp);
        float wx = xp - x0f, wy = yp - y0f;
        int x0 = (int)x0f, y0 = (int)y0f;
        int x1 = min(x0 + 1, Wq - 1), y1 = min(y0 + 1, Hq - 1);
        int p00 = ((c * Hq + y0) * Wq + x0) * 2, p01 = ((c * Hq + y0) * Wq + x1) * 2;
        int p10 = ((c * Hq + y1) * Wq + x0) * 2, p11 = ((c * Hq + y1) * Wq + x1) * 2;
        float w00 = (1.f - wx) * (1.f - wy), w01 = wx * (1.f - wy);
        float w10 = (1.f - wx) * wy, w11 = wx * wy;
        float4 a0 = h4[p00], b0 = h4[p01], c0 = h4[p10], d0 = h4[p11];
        float4 a1 = h4[p00 + 1], b1 = h4[p01 + 1], c1 = h4[p10 + 1], d1 = h4[p11 + 1];
        float4 r0, r1;
        r0.x = w00 * a0.x + w01 * b0.x + w10 * c0.x + w11 * d0.x;
        r0.y = w00 * a0.y + w01 * b0.y + w10 * c0.y + w11 * d0.y;
        r0.z = w00 * a0.z + w01 * b0.z + w10 * c0.z + w11 * d0.z;
        r0.w = w00 * a0.w + w01 * b0.w + w10 * c0.w + w11 * d0.w;
        r1.x = w00 * a1.x + w01 * b1.x + w10 * c1.x + w11 * d1.x;
        r1.y = w00 * a1.y + w01 * b1.y + w10 * c1.y + w11 * d1.y;
        r1.z = w00 * a1.z + w01 * b1.z + w10 * c1.z + w11 * d1.z;
        r1.w = w00 * a1.w + w01 * b1.w + w10 * c1.w + w11 * d1.w;
        float ssum = r0.x + r0.y + r0.z + r0.w + r1.x + r1.y + r1.z + r1.w;
        float xt = xl[c * HWq + y * Wq + x];
        r0.x += xt; r0.y += xt; r0.z += xt; r0.w += xt;
        r1.x += xt; r1.y += xt; r1.z += xt; r1.w += xt;
        int po = ((c * Hq + y) * Wq + x) * 2;
        o4[po] = r0;
        o4[po + 1] = r1;
        float meanv = ssum * 0.125f + xt;
        xf[(c * Hq + y) * Wq + x] = meanv;
        partial += meanv;
    }
    __shared__ float sred[256];
    sred[tid] = partial;
    __syncthreads();
    for (int s = 128; s > 0; s >>= 1) {
        if (tid < s) sred[tid] += sred[tid + s];
        __syncthreads();
    }
    if (tid == 0) rowsum[blockIdx.x] = sred[0];
}

// SE gate (recomputed per block from rowsums) + apply: out = xf * gate
__global__ void k_apply(const float* __restrict__ xf, const float* __restrict__ rowsum,
                        const float* __restrict__ sw1, const float* __restrict__ sb1,
                        const float* __restrict__ sw2, const float* __restrict__ sb2,
                        float* __restrict__ out_l) {
    int c = blockIdx.x / Hq, y = blockIdx.x % Hq;
    float ym[Cq];
#pragma unroll
    for (int i = 0; i < Cq; i++) ym[i] = rowsum[i * Hq + y] * (1.0f / Wq);
    float z[SEM];
#pragma unroll
    for (int m = 0; m < SEM; m++) {
        float a = sb1[m];
#pragma unroll
        for (int i = 0; i < Cq; i++) a = fmaf(sw1[m * Cq + i], ym[i], a);
        z[m] = a * sigmoidf_(a);
    }
    float a = sb2[c];
#pragma unroll
    for (int m = 0; m < SEM; m++) a = fmaf(sw2[c * SEM + m], z[m], a);
    float gv = sigmoidf_(a);
    const float4* s4 = (const float4*)(xf + (size_t)(c * Hq + y) * Wq);
    float4* d4 = (float4*)(out_l + (size_t)(c * Hq + y) * Wq);
    for (int i = threadIdx.x; i < Wq / 4; i += blockDim.x) {
        float4 v = s4[i];
        v.x *= gv; v.y *= gv; v.z *= gv; v.w *= gv;
        d4[i] = v;
    }
}

extern "C" void kernel_launch(void* const* d_in, const int* in_sizes, int n_in,
                              void* d_out, int out_size, void* d_ws, size_t ws_size,
                              hipStream_t stream) {
    const float* x = (const float*)d_in[0];
    const float* h0 = (const float*)d_in[1];
    const float* listT = (const float*)d_in[2];
    const float* hw1 = (const float*)d_in[3];
    const float* hb1 = (const float*)d_in[4];
    const float* hw2 = (const float*)d_in[5];
    const float* hb2 = (const float*)d_in[6];
    const float* sw1 = (const float*)d_in[7];
    const float* sb1 = (const float*)d_in[8];
    const float* sw2 = (const float*)d_in[9];
    const float* sb2 = (const float*)d_in[10];
    float* out = (float*)d_out;
    float* ws = (float*)d_ws;

    size_t off = 0;
    float* flow = ws + off; off += (size_t)Lq * 2 * HWq;   // 7.4 MB
    float* f    = ws + off; off += (size_t)Lq * 2 * HWq;   // 7.4 MB
    float* f1   = ws + off; off += (size_t)Lq * MIDq * HWq; // 29.5 MB
    float* hA   = ws + off; off += (size_t)Cq * HWq * Rq;  // 59 MB
    float* hB   = ws + off; off += (size_t)Cq * HWq * Rq;  // 59 MB
    float* xf   = ws + off; off += (size_t)Cq * HWq;       // 7.4 MB
    float* rows = ws + off; off += (size_t)Cq * Hq;        // 15 KB

    const int nthr = 256;
    const int nLHW = Lq * HWq;
    k_conv1<<<(nLHW + nthr - 1) / nthr, nthr, 0, stream>>>(x, hw1, hb1, f1);
    k_conv2<<<(nLHW + nthr - 1) / nthr, nthr, 0, stream>>>(f1, hw2, hb2, f);
    k_flow<<<(nLHW + nthr - 1) / nthr, nthr, 0, stream>>>(f, flow);

    const float* hin = h0;
    float* bufs[2] = {hA, hB};
    for (int l = 0; l < Lq; l++) {
        float* hout = bufs[l & 1];
        k_warp<<<Cq * Hq, 256, 0, stream>>>(hin, hout, flow + (size_t)l * 2 * HWq,
                                            x + (size_t)l * Cq * HWq, listT, l, xf, rows);
        k_apply<<<Cq * Hq, 128, 0, stream>>>(xf, rows, sw1, sb1, sw2, sb2,
                                             out + (size_t)l * Cq * HWq);
        hin = hout;
    }
}

// Round 2
// 546.409 us; speedup vs baseline: 1.1716x; 1.1716x over previous
//
#include <hip/hip_runtime.h>
#include <math.h>

constexpr int Lq = 8, Cq = 16, Hq = 240, Wq = 480, Rq = 8, MIDq = 8, SEM = 4;
constexpr int HWq = Hq * Wq;

__device__ __forceinline__ float sigmoidf_(float v) { return 1.0f / (1.0f + expf(-v)); }

// conv1: x (L,16,H,W) -> silu -> f1 (L,8,H,W), 3x3 SAME zero-pad.
// block = one (l,y) row, 128 threads, 4 px/thread. l = blockIdx&7 -> XCD-affine.
__global__ void k_conv1(const float* __restrict__ x, const float* __restrict__ w1,
                        const float* __restrict__ b1, float* __restrict__ f1) {
    int b = blockIdx.x;
    int l = b & 7, y = b >> 3;
    int t = threadIdx.x;
    if (t >= Wq / 4) return;
    int xi = t * 4;
    float acc[MIDq][4];
#pragma unroll
    for (int m = 0; m < MIDq; m++) {
        float bv = b1[m];
#pragma unroll
        for (int o = 0; o < 4; o++) acc[m][o] = bv;
    }
#pragma unroll 1
    for (int ic = 0; ic < Cq; ic++) {
        const float* xin = x + (size_t)(l * Cq + ic) * HWq;
        const float* wrow = w1 + ic * 9;
#pragma unroll
        for (int r = 0; r < 3; r++) {
            int yy = y + r - 1;
            if (yy < 0 || yy >= Hq) continue;   // zero pad (uniform branch)
            const float* rp = xin + yy * Wq;
            float4 mid = *(const float4*)(rp + xi);
            float lft = (xi > 0) ? rp[xi - 1] : 0.f;
            float rgt = (xi + 4 < Wq) ? rp[xi + 4] : 0.f;
            float in6[6] = {lft, mid.x, mid.y, mid.z, mid.w, rgt};
#pragma unroll
            for (int m = 0; m < MIDq; m++) {
                const float* wp = wrow + m * (Cq * 9) + r * 3;   // uniform -> s_load
                float w0 = wp[0], w1v = wp[1], w2 = wp[2];
#pragma unroll
                for (int o = 0; o < 4; o++)
                    acc[m][o] = fmaf(w0, in6[o],
                                fmaf(w1v, in6[o + 1],
                                fmaf(w2, in6[o + 2], acc[m][o])));
            }
        }
    }
    size_t rowoff = (size_t)y * Wq + xi;
#pragma unroll
    for (int m = 0; m < MIDq; m++) {
        float4 v;
        float a0 = acc[m][0], a1 = acc[m][1], a2 = acc[m][2], a3 = acc[m][3];
        v.x = a0 * sigmoidf_(a0);
        v.y = a1 * sigmoidf_(a1);
        v.z = a2 * sigmoidf_(a2);
        v.w = a3 * sigmoidf_(a3);
        *(float4*)(f1 + (size_t)(l * MIDq + m) * HWq + rowoff) = v;
    }
}

// conv2: f1 (L,8,H,W) -> f (L,2,H,W), 3x3 SAME zero-pad. Same structure.
__global__ void k_conv2(const float* __restrict__ f1, const float* __restrict__ w2,
                        const float* __restrict__ b2, float* __restrict__ f) {
    int b = blockIdx.x;
    int l = b & 7, y = b >> 3;
    int t = threadIdx.x;
    if (t >= Wq / 4) return;
    int xi = t * 4;
    float acc[2][4];
#pragma unroll
    for (int m = 0; m < 2; m++) {
        float bv = b2[m];
#pragma unroll
        for (int o = 0; o < 4; o++) acc[m][o] = bv;
    }
#pragma unroll 1
    for (int ic = 0; ic < MIDq; ic++) {
        const float* fin = f1 + (size_t)(l * MIDq + ic) * HWq;
        const float* wrow = w2 + ic * 9;
#pragma unroll
        for (int r = 0; r < 3; r++) {
            int yy = y + r - 1;
            if (yy < 0 || yy >= Hq) continue;
            const float* rp = fin + yy * Wq;
            float4 mid = *(const float4*)(rp + xi);
            float lft = (xi > 0) ? rp[xi - 1] : 0.f;
            float rgt = (xi + 4 < Wq) ? rp[xi + 4] : 0.f;
            float in6[6] = {lft, mid.x, mid.y, mid.z, mid.w, rgt};
#pragma unroll
            for (int m = 0; m < 2; m++) {
                const float* wp = wrow + m * (MIDq * 9) + r * 3;
                float w0 = wp[0], w1v = wp[1], w2v = wp[2];
#pragma unroll
                for (int o = 0; o < 4; o++)
                    acc[m][o] = fmaf(w0, in6[o],
                                fmaf(w1v, in6[o + 1],
                                fmaf(w2v, in6[o + 2], acc[m][o])));
            }
        }
    }
    size_t rowoff = (size_t)y * Wq + xi;
#pragma unroll
    for (int m = 0; m < 2; m++) {
        float4 v = {acc[m][0], acc[m][1], acc[m][2], acc[m][3]};
        *(float4*)(f + (size_t)(l * 2 + m) * HWq + rowoff) = v;
    }
}

// sobel (wrap-x, edge-y) + metric + tanh -> flow (L,2,H,W)
__global__ void k_flow(const float* __restrict__ f, float* __restrict__ flow) {
    int idx = blockIdx.x * blockDim.x + threadIdx.x;
    if (idx >= Lq * HWq) return;
    int l = idx / HWq, rem = idx % HWq, y = rem / Wq, x = rem % Wq;
    const float* phi = f + (size_t)(l * 2 + 0) * HWq;
    const float* psi = f + (size_t)(l * 2 + 1) * HWq;
    float ph[3][3], ps[3][3];
#pragma unroll
    for (int i = 0; i < 3; i++) {
        int yy = y + i - 1;
        yy = yy < 0 ? 0 : (yy >= Hq ? Hq - 1 : yy);
#pragma unroll
        for (int j = 0; j < 3; j++) {
            int xx = x + j - 1;
            xx = (xx + Wq) % Wq;
            ph[i][j] = phi[yy * Wq + xx];
            ps[i][j] = psi[yy * Wq + xx];
        }
    }
    float gxp = (ph[0][2] - ph[0][0]) + 2.f * (ph[1][2] - ph[1][0]) + (ph[2][2] - ph[2][0]);
    float gyp = (ph[2][0] + 2.f * ph[2][1] + ph[2][2]) - (ph[0][0] + 2.f * ph[0][1] + ph[0][2]);
    float gxs = (ps[0][2] - ps[0][0]) + 2.f * (ps[1][2] - ps[1][0]) + (ps[2][2] - ps[2][0]);
    float gys = (ps[2][0] + 2.f * ps[2][1] + ps[2][2]) - (ps[0][0] + 2.f * ps[0][1] + ps[0][2]);
    float latf = (float)(-M_PI * 0.5 + (double)y * (M_PI / (double)(Hq - 1)));
    float metric = (float)(1.0 / (cos((double)latf) + 1e-6));
    float u = gxp * metric - gys;
    float v = gyp + gxs * metric;
    flow[(size_t)(l * 2 + 0) * HWq + rem] = tanhf(u);
    flow[(size_t)(l * 2 + 1) * HWq + rem] = tanhf(v);
}

// warp (bilinear, border clamp) + add x_t + mean over R + row partial sums
__global__ void k_warp(const float* __restrict__ hin, float* __restrict__ hout,
                       const float* __restrict__ flow_l, const float* __restrict__ xl,
                       const float* __restrict__ listT, int l,
                       float* __restrict__ xf, float* __restrict__ rowsum) {
    int c = blockIdx.x / Hq, y = blockIdx.x % Hq;
    int tid = threadIdx.x;
    float dt = listT[l];
    float gyn = y * (2.0f / (Hq - 1)) - 1.0f;
    const float4* h4 = (const float4*)hin;
    float4* o4 = (float4*)hout;
    float partial = 0.f;
    for (int x = tid; x < Wq; x += blockDim.x) {
        float u = flow_l[y * Wq + x];
        float v = flow_l[HWq + y * Wq + x];
        float gxn = x * (2.0f / (Wq - 1)) - 1.0f;
        float gx = gxn - u * dt;
        float gy = gyn - v * dt;
        float xp = (gx + 1.0f) * (Wq * 0.5f) - 0.5f;
        float yp = (gy + 1.0f) * (Hq * 0.5f) - 0.5f;
        xp = fminf(fmaxf(xp, 0.0f), (float)(Wq - 1));
        yp = fminf(fmaxf(yp, 0.0f), (float)(Hq - 1));
        float x0f = floorf(xp), y0f = floorf(yp);
        float wx = xp - x0f, wy = yp - y0f;
        int x0 = (int)x0f, y0 = (int)y0f;
        int x1 = min(x0 + 1, Wq - 1), y1 = min(y0 + 1, Hq - 1);
        int p00 = ((c * Hq + y0) * Wq + x0) * 2, p01 = ((c * Hq + y0) * Wq + x1) * 2;
        int p10 = ((c * Hq + y1) * Wq + x0) * 2, p11 = ((c * Hq + y1) * Wq + x1) * 2;
        float w00 = (1.f - wx) * (1.f - wy), w01 = wx * (1.f - wy);
        float w10 = (1.f - wx) * wy, w11 = wx * wy;
        float4 a0 = h4[p00], b0 = h4[p01], c0 = h4[p10], d0 = h4[p11];
        float4 a1 = h4[p00 + 1], b1 = h4[p01 + 1], c1 = h4[p10 + 1], d1 = h4[p11 + 1];
        float4 r0, r1;
        r0.x = w00 * a0.x + w01 * b0.x + w10 * c0.x + w11 * d0.x;
        r0.y = w00 * a0.y + w01 * b0.y + w10 * c0.y + w11 * d0.y;
        r0.z = w00 * a0.z + w01 * b0.z + w10 * c0.z + w11 * d0.z;
        r0.w = w00 * a0.w + w01 * b0.w + w10 * c0.w + w11 * d0.w;
        r1.x = w00 * a1.x + w01 * b1.x + w10 * c1.x + w11 * d1.x;
        r1.y = w00 * a1.y + w01 * b1.y + w10 * c1.y + w11 * d1.y;
        r1.z = w00 * a1.z + w01 * b1.z + w10 * c1.z + w11 * d1.z;
        r1.w = w00 * a1.w + w01 * b1.w + w10 * c1.w + w11 * d1.w;
        float ssum = r0.x + r0.y + r0.z + r0.w + r1.x + r1.y + r1.z + r1.w;
        float xt = xl[c * HWq + y * Wq + x];
        r0.x += xt; r0.y += xt; r0.z += xt; r0.w += xt;
        r1.x += xt; r1.y += xt; r1.z += xt; r1.w += xt;
        int po = ((c * Hq + y) * Wq + x) * 2;
        o4[po] = r0;
        o4[po + 1] = r1;
        float meanv = ssum * 0.125f + xt;
        xf[(c * Hq + y) * Wq + x] = meanv;
        partial += meanv;
    }
    __shared__ float sred[256];
    sred[tid] = partial;
    __syncthreads();
    for (int s = 128; s > 0; s >>= 1) {
        if (tid < s) sred[tid] += sred[tid + s];
        __syncthreads();
    }
    if (tid == 0) rowsum[blockIdx.x] = sred[0];
}

// SE gate (recomputed per block from rowsums) + apply: out = xf * gate
__global__ void k_apply(const float* __restrict__ xf, const float* __restrict__ rowsum,
                        const float* __restrict__ sw1, const float* __restrict__ sb1,
                        const float* __restrict__ sw2, const float* __restrict__ sb2,
                        float* __restrict__ out_l) {
    int c = blockIdx.x / Hq, y = blockIdx.x % Hq;
    float ym[Cq];
#pragma unroll
    for (int i = 0; i < Cq; i++) ym[i] = rowsum[i * Hq + y] * (1.0f / Wq);
    float z[SEM];
#pragma unroll
    for (int m = 0; m < SEM; m++) {
        float a = sb1[m];
#pragma unroll
        for (int i = 0; i < Cq; i++) a = fmaf(sw1[m * Cq + i], ym[i], a);
        z[m] = a * sigmoidf_(a);
    }
    float a = sb2[c];
#pragma unroll
    for (int m = 0; m < SEM; m++) a = fmaf(sw2[c * SEM + m], z[m], a);
    float gv = sigmoidf_(a);
    const float4* s4 = (const float4*)(xf + (size_t)(c * Hq + y) * Wq);
    float4* d4 = (float4*)(out_l + (size_t)(c * Hq + y) * Wq);
    for (int i = threadIdx.x; i < Wq / 4; i += blockDim.x) {
        float4 v = s4[i];
        v.x *= gv; v.y *= gv; v.z *= gv; v.w *= gv;
        d4[i] = v;
    }
}

extern "C" void kernel_launch(void* const* d_in, const int* in_sizes, int n_in,
                              void* d_out, int out_size, void* d_ws, size_t ws_size,
                              hipStream_t stream) {
    const float* x = (const float*)d_in[0];
    const float* h0 = (const float*)d_in[1];
    const float* listT = (const float*)d_in[2];
    const float* hw1 = (const float*)d_in[3];
    const float* hb1 = (const float*)d_in[4];
    const float* hw2 = (const float*)d_in[5];
    const float* hb2 = (const float*)d_in[6];
    const float* sw1 = (const float*)d_in[7];
    const float* sb1 = (const float*)d_in[8];
    const float* sw2 = (const float*)d_in[9];
    const float* sb2 = (const float*)d_in[10];
    float* out = (float*)d_out;
    float* ws = (float*)d_ws;

    size_t off = 0;
    float* flow = ws + off; off += (size_t)Lq * 2 * HWq;
    float* f    = ws + off; off += (size_t)Lq * 2 * HWq;
    float* f1   = ws + off; off += (size_t)Lq * MIDq * HWq;
    float* hA   = ws + off; off += (size_t)Cq * HWq * Rq;
    float* hB   = ws + off; off += (size_t)Cq * HWq * Rq;
    float* xf   = ws + off; off += (size_t)Cq * HWq;
    float* rows = ws + off; off += (size_t)Cq * Hq;

    k_conv1<<<Lq * Hq, 128, 0, stream>>>(x, hw1, hb1, f1);
    k_conv2<<<Lq * Hq, 128, 0, stream>>>(f1, hw2, hb2, f);
    k_flow<<<(Lq * HWq + 255) / 256, 256, 0, stream>>>(f, flow);

    const float* hin = h0;
    float* bufs[2] = {hA, hB};
    for (int l = 0; l < Lq; l++) {
        float* hout = bufs[l & 1];
        k_warp<<<Cq * Hq, 256, 0, stream>>>(hin, hout, flow + (size_t)l * 2 * HWq,
                                            x + (size_t)l * Cq * HWq, listT, l, xf, rows);
        k_apply<<<Cq * Hq, 128, 0, stream>>>(xf, rows, sw1, sb1, sw2, sb2,
                                             out + (size_t)l * Cq * HWq);
        hin = hout;
    }
}